// Round 9
// baseline (259.582 us; speedup 1.0000x reference)
//
#include <hip/hip_runtime.h>

// SA_Head: B=4, S=4096, E=256, H=64
//   out = softmax((emb@wq)(emb@wk)^T / 16) (emb@wv)
// R9: attn -> 16-q-row blocks, NO split-K (reduce kernel + po/pml deleted;
// attn writes out directly). oacc shrinks 64->16 AGPRs so the R5 prefetch
// pipeline fits in <128 regs without spill (R8 lesson). proj -> wave-
// autonomous full-E GEMM: A-frags packed in registers, 96 MFMAs/wave, no LDS.

typedef short short4v __attribute__((ext_vector_type(4)));
typedef short short8v __attribute__((ext_vector_type(8)));
typedef float floatx4 __attribute__((ext_vector_type(4)));
typedef unsigned short u16;
typedef unsigned int u32;

#define SEQ 4096
#define EMB 256
#define HD 64

static __device__ __forceinline__ u16 f2bf(float x) {
    union { float f; unsigned u; } v; v.f = x;
    unsigned r = v.u + 0x7FFFu + ((v.u >> 16) & 1u);
    return (u16)(r >> 16);
}

// round-to-nearest bf16 pair pack: int add 0x8000 + byte-perm
static __device__ __forceinline__ u32 pack_rn(float lo, float hi) {
    union { float f; u32 u; } a, b;
    a.f = lo; b.f = hi;
    return __builtin_amdgcn_perm(b.u + 0x8000u, a.u + 0x8000u, 0x07060302u);
}

// ---------------- W prep: fragment-major Wt --------------------------------------
// wt frag order: ((nt*8+kc)*64+lane)*8+j holds W[e=kc*32+lq*8+j][col=nt*16+ln15]*s
__global__ __launch_bounds__(256) void prep_w(
    const float* __restrict__ wk, const float* __restrict__ wq, const float* __restrict__ wv,
    u16* __restrict__ wt) {
    const int nt = blockIdx.x;   // 0..11
    const int t = threadIdx.x;
#pragma unroll
    for (int ss = 0; ss < 2; ++ss) {
        int slot = t + ss * 256;
        int kc = slot >> 6, lane = slot & 63;
        int ln15 = lane & 15, lq = lane >> 4;
        int cg = nt * 16 + ln15;
        int mat = cg >> 6, col = cg & 63;
        const float* W = (mat == 0) ? wq : (mat == 1) ? wk : wv;
        const float s = (mat == 0) ? 0.0625f * 1.44269504088896f : 1.0f;
        u32 w4[4];
#pragma unroll
        for (int p = 0; p < 4; ++p) {
            int e0 = kc * 32 + lq * 8 + p * 2;
            u16 lo = f2bf(W[(e0 + 0) * HD + col] * s);
            u16 hi = f2bf(W[(e0 + 1) * HD + col] * s);
            w4[p] = (u32)lo | ((u32)hi << 16);
        }
        u32* dst = (u32*)wt + ((size_t)(nt * 8 + kc) * 64 + lane) * 4;
        *(uint4*)dst = make_uint4(w4[0], w4[1], w4[2], w4[3]);
    }
}

// ---------------- projection: wave-autonomous full-E bf16 MFMA GEMM ----------------
// 1024 blocks x 64 thr (1 wave). Wave g: rows [16g,16g+16), all 192 out cols.
// A staged in registers (32 VGPR); 96 MFMAs/wave; emb read exactly once.
__global__ __launch_bounds__(64, 4) void proj_mfma(
    const float* __restrict__ emb, const u16* __restrict__ wt,
    u16* __restrict__ qb, u16* __restrict__ kb, u16* __restrict__ vbt) {
    const int lane = threadIdx.x;
    const int ln15 = lane & 15;
    const int lq = lane >> 4;
    const size_t row0 = (size_t)blockIdx.x * 16;

    const float* __restrict__ ap = emb + (row0 + ln15) * EMB + lq * 8;
    short8v af[8];
#pragma unroll
    for (int kc = 0; kc < 8; ++kc) {
        float4 a0 = *(const float4*)(ap + kc * 32);
        float4 a1 = *(const float4*)(ap + kc * 32 + 4);
        union { u32 u[4]; short8v s; } av;
        av.u[0] = pack_rn(a0.x, a0.y);
        av.u[1] = pack_rn(a0.z, a0.w);
        av.u[2] = pack_rn(a1.x, a1.y);
        av.u[3] = pack_rn(a1.z, a1.w);
        af[kc] = av.s;
    }

    // n-tiles in pairs for MFMA ILP
#pragma unroll
    for (int np = 0; np < 6; ++np) {
        floatx4 acc0 = { 0.f, 0.f, 0.f, 0.f };
        floatx4 acc1 = { 0.f, 0.f, 0.f, 0.f };
        const int nt0 = np * 2, nt1 = np * 2 + 1;
#pragma unroll
        for (int kc = 0; kc < 8; ++kc) {
            short8v b0 = *(const short8v*)(wt + (((size_t)(nt0 * 8 + kc) * 64 + lane) * 8));
            short8v b1 = *(const short8v*)(wt + (((size_t)(nt1 * 8 + kc) * 64 + lane) * 8));
            acc0 = __builtin_amdgcn_mfma_f32_16x16x32_bf16(af[kc], b0, acc0, 0, 0, 0);
            acc1 = __builtin_amdgcn_mfma_f32_16x16x32_bf16(af[kc], b1, acc1, 0, 0, 0);
        }
#pragma unroll
        for (int h = 0; h < 2; ++h) {
            const floatx4& acc = h ? acc1 : acc0;
            const int nt = h ? nt1 : nt0;
            const int mat = nt >> 2;
            const int col = (nt & 3) * 16 + ln15;
            if (mat < 2) {
                u16* __restrict__ O = (mat == 0) ? qb : kb;
#pragma unroll
                for (int r = 0; r < 4; ++r)
                    O[(row0 + lq * 4 + r) * HD + col] = f2bf(acc[r]);
            } else {
                ushort4 o4;
                o4.x = f2bf(acc[0]); o4.y = f2bf(acc[1]);
                o4.z = f2bf(acc[2]); o4.w = f2bf(acc[3]);
                size_t bidx = row0 >> 12;
                size_t sl = (row0 & 4095) + lq * 4;
                *(ushort4*)&vbt[(bidx * 64 + col) * SEQ + sl] = o4;
            }
        }
    }
}

// ---------------- flash attention: 16-q-row blocks, full K sweep, no split ---------
// block = b*256 + qt (q0 = qt*16); 4 waves; wave w owns keys [tt*64+16w, +16).
// S^T = K.Q^T (16x16x32); P = exp2 packed in regs; O^T += V^T.P (16x16x16).
// Live set ~90 regs (oacc only 16 AGPR) -> 4 waves/SIMD, no spill.
__global__ __launch_bounds__(256, 4) void attn_kernel(
    const u16* __restrict__ qb, const u16* __restrict__ kb, const u16* __restrict__ vbt,
    float* __restrict__ out) {
    __shared__ float ored[4][64 * 17];   // per-wave O^T slabs, h-stride 17
    __shared__ float lred[64];           // [wave*16 + qrow]

    const int t = threadIdx.x;
    const int lane = t & 63;
    const int wave = t >> 6;
    const int ln15 = lane & 15;
    const int lq = lane >> 4;

    const int blk = blockIdx.x;
    const int b = blk >> 8;
    const int q0 = (blk & 255) * 16;

    const u16* __restrict__ qpb = qb + ((size_t)b * SEQ + q0) * HD;
    const u16* __restrict__ kpb = kb + (size_t)b * SEQ * HD;
    const u16* __restrict__ vpb = vbt + (size_t)b * HD * SEQ;

    // Q B-frags in registers (loop-invariant): rows=ln15, k=lq*8+j (+32)
    short8v qf0 = *(const short8v*)(qpb + (size_t)ln15 * HD + lq * 8);
    short8v qf1 = *(const short8v*)(qpb + (size_t)ln15 * HD + 32 + lq * 8);

    floatx4 oacc[4];
#pragma unroll
    for (int ht = 0; ht < 4; ++ht) {
        floatx4 z = { 0.f, 0.f, 0.f, 0.f };
        oacc[ht] = z;
    }
    float lacc = 0.f;

    int kw = wave * 16;
    short8v kf0 = *(const short8v*)(kpb + (size_t)(kw + ln15) * HD + lq * 8);
    short8v kf1 = *(const short8v*)(kpb + (size_t)(kw + ln15) * HD + 32 + lq * 8);
    short4v vf[4];
#pragma unroll
    for (int ht = 0; ht < 4; ++ht)
        vf[ht] = *(const short4v*)(vpb + (size_t)(ht * 16 + ln15) * SEQ + kw + lq * 4);

    for (int tt = 0; tt < 64; ++tt) {
        // prefetch next tile (last iter over-reads into adjacent ws - safe)
        const int kwn = kw + 64;
        short8v nk0 = *(const short8v*)(kpb + (size_t)(kwn + ln15) * HD + lq * 8);
        short8v nk1 = *(const short8v*)(kpb + (size_t)(kwn + ln15) * HD + 32 + lq * 8);
        short4v nv[4];
#pragma unroll
        for (int ht = 0; ht < 4; ++ht)
            nv[ht] = *(const short4v*)(vpb + (size_t)(ht * 16 + ln15) * SEQ + kwn + lq * 4);

        // S^T: D[m=key=lq*4+r][n=qrow=ln15]
        floatx4 z = { 0.f, 0.f, 0.f, 0.f };
        floatx4 s = __builtin_amdgcn_mfma_f32_16x16x32_bf16(kf0, qf0, z, 0, 0, 0);
        s = __builtin_amdgcn_mfma_f32_16x16x32_bf16(kf1, qf1, s, 0, 0, 0);

        float p0 = __builtin_amdgcn_exp2f(s[0]);
        float p1 = __builtin_amdgcn_exp2f(s[1]);
        float p2 = __builtin_amdgcn_exp2f(s[2]);
        float p3 = __builtin_amdgcn_exp2f(s[3]);
        lacc += (p0 + p1) + (p2 + p3);
        union { u32 u[2]; short4v s4; } pk;
        pk.u[0] = pack_rn(p0, p1);
        pk.u[1] = pack_rn(p2, p3);

#pragma unroll
        for (int ht = 0; ht < 4; ++ht)
            oacc[ht] = __builtin_amdgcn_mfma_f32_16x16x16bf16_1k(
                vf[ht], pk.s4, oacc[ht], 0, 0, 0);

        kw = kwn;
        kf0 = nk0; kf1 = nk1;
#pragma unroll
        for (int ht = 0; ht < 4; ++ht) vf[ht] = nv[ht];
    }

    // ---- epilogue: per-wave slabs, one barrier ----
    lacc += __shfl_xor(lacc, 16);
    lacc += __shfl_xor(lacc, 32);
    if (lq == 0) lred[wave * 16 + ln15] = lacc;

#pragma unroll
    for (int ht = 0; ht < 4; ++ht)
#pragma unroll
        for (int r = 0; r < 4; ++r)
            ored[wave][(ht * 16 + lq * 4 + r) * 17 + ln15] = oacc[ht][r];
    __syncthreads();

    // combine 4 waves, normalize, store fp32 out[q0+q][h]
    const int q = t >> 4, h4 = (t & 15) * 4;
    const float L = lred[q] + lred[16 + q] + lred[32 + q] + lred[48 + q];
    const float inv = 1.0f / L;
    float4 r;
    r.x = (ored[0][(h4 + 0) * 17 + q] + ored[1][(h4 + 0) * 17 + q]
         + ored[2][(h4 + 0) * 17 + q] + ored[3][(h4 + 0) * 17 + q]) * inv;
    r.y = (ored[0][(h4 + 1) * 17 + q] + ored[1][(h4 + 1) * 17 + q]
         + ored[2][(h4 + 1) * 17 + q] + ored[3][(h4 + 1) * 17 + q]) * inv;
    r.z = (ored[0][(h4 + 2) * 17 + q] + ored[1][(h4 + 2) * 17 + q]
         + ored[2][(h4 + 2) * 17 + q] + ored[3][(h4 + 2) * 17 + q]) * inv;
    r.w = (ored[0][(h4 + 3) * 17 + q] + ored[1][(h4 + 3) * 17 + q]
         + ored[2][(h4 + 3) * 17 + q] + ored[3][(h4 + 3) * 17 + q]) * inv;
    *(float4*)&out[((size_t)b * SEQ + q0 + q) * HD + h4] = r;
}

extern "C" void kernel_launch(void* const* d_in, const int* in_sizes, int n_in,
                              void* d_out, int out_size, void* d_ws, size_t ws_size,
                              hipStream_t stream) {
    const float* emb = (const float*)d_in[0];
    const float* wk  = (const float*)d_in[1];
    const float* wq  = (const float*)d_in[2];
    const float* wv  = (const float*)d_in[3];

    // ws: qb 2M @0, kb 2M @2M, vbt 2M @4M, wt 96K @6M
    u16* qb  = (u16*)d_ws;
    u16* kb  = (u16*)((char*)d_ws + (size_t)2 * 1024 * 1024);
    u16* vbt = (u16*)((char*)d_ws + (size_t)4 * 1024 * 1024);
    u16* wt  = (u16*)((char*)d_ws + (size_t)6 * 1024 * 1024);
    float* out = (float*)d_out;

    prep_w<<<12, 256, 0, stream>>>(wk, wq, wv, wt);
    proj_mfma<<<1024, 64, 0, stream>>>(emb, wt, qb, kb, vbt);
    attn_kernel<<<1024, 256, 0, stream>>>(qb, kb, vbt, out);
}